// Round 13
// baseline (216.880 us; speedup 1.0000x reference)
//
#include <hip/hip_runtime.h>
#include <math.h>

// NoRefRetIQANet: cosine top-K retrieval, two-phase.
// Phase 1 (approx): score[b,n] ~= hh + hl/4096 via MFMA (A=f16(q) hi-only,
//   B split hi/lo in-kernel from raw f32; only the lh term is dropped).
//   Exact f32 DB norms folded into staging conversion. Selects top-16/row.
// Phase 2 (exact): fp32 rerank of 16 candidates -> top-9 -> metrics gather.
//   (rerank tail verified absmax 0.0 in rounds 7-9)
// Round-13 A/B experiment: R12 score structure FROZEN (ring-2, 2-barrier,
// stage-after-compute, counted vmcnt) with ONLY A-staging cut to hi-only
// (24 KB/step vs 32; 721 MB total staged vs 962). Tests whether R8's
// regression was ring-3 (exonerates hi-only) or hi-only itself.
// ws: semp0[64][20000] f32, semp1, dstp, nsq0/1/d[20000], apack_sem(hi),
//     apack_dst(hi), cand_val[128][128], cand_idx[128][128], idx_ws[128][16].
// d_out: [0,64) result, [64, 64+64*18) retrieved.

typedef _Float16 half8 __attribute__((ext_vector_type(8)));
typedef float    f32x4 __attribute__((ext_vector_type(4)));

#define NDB   20000
#define NQ    64
#define KSEM  4096
#define KDST  2048
#define KC    2048
#define NSTEP (KC / 64)     // 32 steps of 64
#define BN    64
#define NTILE 313           // ceil(20000/64); last tile row-clamped
#define K2    16
#define SEG   8
#define SEGSZ (NDB / SEG)   // 2500

__device__ __forceinline__ void async_cp16(const void* g, void* l) {
    __builtin_amdgcn_global_load_lds(
        (const __attribute__((address_space(1))) void*)g,
        (__attribute__((address_space(3))) void*)l, 16, 0, 0);
}

// ---------------------------------------------------------------------------
// qsplit: fp32 queries -> fragment-ordered, bank-swizzled f16 HI pack.
// Unit u (16B = half8) within a 32-k section: u = 4*row + (((row>>1)&3)^kg);
// section = 256 units. (R7/R8 verbatim, verified)
// ---------------------------------------------------------------------------
__global__ __launch_bounds__(256) void qsplit_kernel(
    const float* __restrict__ fc, const float* __restrict__ fd,
    _Float16* __restrict__ apack_sem, _Float16* __restrict__ apack_dst)
{
    const int idx = (int)blockIdx.x * 256 + (int)threadIdx.x;
    const int NSEM8 = NQ * KSEM / 8;            // 32768
    const float* src; _Float16* dst; int row, g8, K;
    if (idx < NSEM8) { src = fc; dst = apack_sem; K = KSEM; row = idx >> 9; g8 = idx & 511; }
    else { const int j = idx - NSEM8; src = fd; dst = apack_dst; K = KDST; row = j >> 8; g8 = j & 255; }

    const float* p = src + (size_t)row * K + g8 * 8;
    const float4 v0 = ((const float4*)p)[0];
    const float4 v1 = ((const float4*)p)[1];
    const float xs[8] = {v0.x, v0.y, v0.z, v0.w, v1.x, v1.y, v1.z, v1.w};
    half8 hi;
    #pragma unroll
    for (int e = 0; e < 8; ++e) hi[e] = (_Float16)xs[e];
    const int sec = g8 >> 2, kg = g8 & 3;
    const int u = (row << 2) + (((row >> 1) & 3) ^ kg);
    ((half8*)dst)[sec * 256 + u] = hi;
}

// ---------------------------------------------------------------------------
// score: 939 blocks = 313 n-tiles x {sem kc0, sem kc1, dst}, uniform KC=2048.
// 256 thr / 4 waves, wave grid 2x2 (qh=w>>1, nh=w&1), each 32q x 32n.
// R12 pacing structure; A hi-only (6 DMA/wave/step, vmcnt(6) gate).
// ---------------------------------------------------------------------------
__global__ __launch_bounds__(256, 3) void score_kernel(
    const float* __restrict__ sdb, const float* __restrict__ ddb,
    const _Float16* __restrict__ apack_sem, const _Float16* __restrict__ apack_dst,
    float* __restrict__ semp0, float* __restrict__ semp1, float* __restrict__ dstp,
    float* __restrict__ nsq0, float* __restrict__ nsq1, float* __restrict__ nsqd)
{
    // A: [buf][sec*2048 + u*8] halves (hi only); 2 bufs x 8 KB
    __shared__ __align__(16) _Float16 A_lds[2][4096];
    // B: [buf][sec*2048 + r*32 + c*4] floats, chunk c XOR-swizzled by row
    __shared__ __align__(16) float    B_lds[2][4096];   // 2 bufs x 16 KB

    const int tid  = threadIdx.x;
    const int lane = tid & 63, w = tid >> 6;
    const int bid  = (int)blockIdx.x;
    const int mkc  = bid / NTILE;         // 0: sem kc0, 1: sem kc1, 2: dst
    const int nt   = bid % NTILE;
    const int n0   = nt * BN;

    const float* D; const _Float16* AP; float *SOUT, *NOUT; int Ks, koff;
    if (mkc == 0)      { D=sdb; AP=apack_sem; SOUT=semp0; NOUT=nsq0; Ks=KSEM; koff=0;  }
    else if (mkc == 1) { D=sdb; AP=apack_sem; SOUT=semp1; NOUT=nsq1; Ks=KSEM; koff=KC; }
    else               { D=ddb; AP=apack_dst; SOUT=dstp;  NOUT=nsqd; Ks=KDST; koff=0;  }

    // --- staging maps (R12 B map verbatim; A hi-only map from R8) ---
    const int u0 = w * 128 + lane,      r0 = u0 >> 3, c0 = (u0 & 7) ^ (r0 & 7);
    const int u1 = u0 + 64,             r1 = u1 >> 3, c1 = (u1 & 7) ^ (r1 & 7);
    const int rg0 = (n0 + r0 < NDB) ? n0 + r0 : NDB - 1;   // clamp tail tile
    const int rg1 = (n0 + r1 < NDB) ? n0 + r1 : NDB - 1;
    const float* gB0 = D + (size_t)rg0 * Ks + koff + c0 * 4;
    const float* gB1 = D + (size_t)rg1 * Ks + koff + c1 * 4;
    const uint4* gA = (const uint4*)AP + ((size_t)koff >> 5) * 256 + w * 64 + lane;

    // --- compute map (R12 verbatim) ---
    const int lr = lane & 15, kg = lane >> 4;
    const int qh = w >> 1, nh = w & 1;
    const int rowA0 = qh * 32 + lr;
    const int rowA1 = rowA0 + 16;
    const int uA0 = ((rowA0 << 2) + (((rowA0 >> 1) & 3) ^ kg)) * 8;
    const int uA1 = ((rowA1 << 2) + (((rowA1 >> 1) & 3) ^ kg)) * 8;
    const int rB0 = nh * 32 + lr;
    const int rB1 = rB0 + 16;
    const int oB00 = rB0 * 32 + (((kg * 2 + 0) ^ (rB0 & 7)) << 2);
    const int oB01 = rB0 * 32 + (((kg * 2 + 1) ^ (rB0 & 7)) << 2);
    const int oB10 = rB1 * 32 + (((kg * 2 + 0) ^ (rB1 & 7)) << 2);
    const int oB11 = rB1 * 32 + (((kg * 2 + 1) ^ (rB1 & 7)) << 2);

    f32x4 acc_h[2][2], acc_x[2][2];
    const f32x4 zz = {0.f, 0.f, 0.f, 0.f};
    #pragma unroll
    for (int i = 0; i < 2; ++i)
        #pragma unroll
        for (int j = 0; j < 2; ++j) { acc_h[i][j] = zz; acc_x[i][j] = zz; }
    float sq0 = 0.f, sq1 = 0.f;

    auto STAGE = [&](int s, int buf) {
        #pragma unroll
        for (int sec = 0; sec < 2; ++sec) {
            const size_t gsec = (size_t)(2 * s + sec);
            async_cp16(gA + gsec * 256,  &A_lds[buf][sec * 2048 + w * 512]);
            async_cp16(gB0 + gsec * 32,  &B_lds[buf][sec * 2048 + w * 512]);
            async_cp16(gB1 + gsec * 32,  &B_lds[buf][sec * 2048 + w * 512 + 256]);
        }
    };

    auto COMPUTE = [&](int buf) {
        #pragma unroll
        for (int sec = 0; sec < 2; ++sec) {
            const float*    Bb = &B_lds[buf][sec * 2048];
            const _Float16* Ab = &A_lds[buf][sec * 2048];
            half8 bh0, bl0, bh1, bl1;
            {   // j = 0
                const f32x4 p = *(const f32x4*)(Bb + oB00);
                const f32x4 q = *(const f32x4*)(Bb + oB01);
                const float xs[8] = {p[0], p[1], p[2], p[3], q[0], q[1], q[2], q[3]};
                #pragma unroll
                for (int e = 0; e < 8; ++e) {
                    const float x = xs[e];
                    sq0 = fmaf(x, x, sq0);
                    const _Float16 h = (_Float16)x;
                    bh0[e] = h;
                    bl0[e] = (_Float16)((x - (float)h) * 4096.0f);
                }
            }
            {   // j = 1
                const f32x4 p = *(const f32x4*)(Bb + oB10);
                const f32x4 q = *(const f32x4*)(Bb + oB11);
                const float xs[8] = {p[0], p[1], p[2], p[3], q[0], q[1], q[2], q[3]};
                #pragma unroll
                for (int e = 0; e < 8; ++e) {
                    const float x = xs[e];
                    sq1 = fmaf(x, x, sq1);
                    const _Float16 h = (_Float16)x;
                    bh1[e] = h;
                    bl1[e] = (_Float16)((x - (float)h) * 4096.0f);
                }
            }
            const half8 ah0 = *(const half8*)(Ab + uA0);
            const half8 ah1 = *(const half8*)(Ab + uA1);

            acc_h[0][0] = __builtin_amdgcn_mfma_f32_16x16x32_f16(ah0, bh0, acc_h[0][0], 0, 0, 0);
            acc_x[0][0] = __builtin_amdgcn_mfma_f32_16x16x32_f16(ah0, bl0, acc_x[0][0], 0, 0, 0);
            acc_h[0][1] = __builtin_amdgcn_mfma_f32_16x16x32_f16(ah0, bh1, acc_h[0][1], 0, 0, 0);
            acc_x[0][1] = __builtin_amdgcn_mfma_f32_16x16x32_f16(ah0, bl1, acc_x[0][1], 0, 0, 0);
            acc_h[1][0] = __builtin_amdgcn_mfma_f32_16x16x32_f16(ah1, bh0, acc_h[1][0], 0, 0, 0);
            acc_x[1][0] = __builtin_amdgcn_mfma_f32_16x16x32_f16(ah1, bl0, acc_x[1][0], 0, 0, 0);
            acc_h[1][1] = __builtin_amdgcn_mfma_f32_16x16x32_f16(ah1, bh1, acc_h[1][1], 0, 0, 0);
            acc_x[1][1] = __builtin_amdgcn_mfma_f32_16x16x32_f16(ah1, bl1, acc_x[1][1], 0, 0, 0);
        }
    };

    // prologue: 2 steps staged (12 DMAs/wave outstanding)
    STAGE(0, 0); STAGE(1, 1);

    for (int s = 0; s < NSTEP; ++s) {
        if (s < NSTEP - 1) { asm volatile("s_waitcnt vmcnt(6)" ::: "memory"); }
        else               { asm volatile("s_waitcnt vmcnt(0)" ::: "memory"); }
        __builtin_amdgcn_s_barrier();      // step-s data visible to all waves
        COMPUTE(s & 1);
        __builtin_amdgcn_s_barrier();      // all waves done reading buf s&1
        if (s + 2 < NSTEP) STAGE(s + 2, s & 1);
    }

    // norms (exact f32 sum-sq of raw B): reduce over kg; qh==0 waves write.
    sq0 += __shfl_xor(sq0, 16); sq0 += __shfl_xor(sq0, 32);
    sq1 += __shfl_xor(sq1, 16); sq1 += __shfl_xor(sq1, 32);
    if (qh == 0 && lane < 16) {
        const int nn0 = n0 + nh * 32 + lane;
        const int nn1 = nn0 + 16;
        if (nn0 < NDB) NOUT[nn0] = sq0;
        if (nn1 < NDB) NOUT[nn1] = sq1;
    }

    // C/D map: col=lane&15, row=(lane>>4)*4+reg (m89-verified)
    #pragma unroll
    for (int i = 0; i < 2; ++i)
        #pragma unroll
        for (int j = 0; j < 2; ++j) {
            const int n = n0 + nh * 32 + j * 16 + lr;
            if (n < NDB) {
                #pragma unroll
                for (int rr = 0; rr < 4; ++rr) {
                    const int q = qh * 32 + i * 16 + kg * 4 + rr;
                    SOUT[(size_t)q * NDB + n] = acc_h[i][j][rr] + acc_x[i][j][rr] * (1.0f / 4096.0f);
                }
            }
        }
}

// ---------------------------------------------------------------------------
// topk_seg: EXACT top-16 per (m,b,segment) by approx score. 1024 blocks.
// Comparator: value desc, index asc (matches lax.top_k). (R12 verbatim)
// ---------------------------------------------------------------------------
__global__ __launch_bounds__(256) void topk_seg_kernel(
    const float* __restrict__ semp0, const float* __restrict__ semp1,
    const float* __restrict__ dstp,
    const float* __restrict__ nsq0, const float* __restrict__ nsq1,
    const float* __restrict__ nsqd,
    float* __restrict__ cand_val, int* __restrict__ cand_idx)
{
    __shared__ float sv[256][K2];
    __shared__ int   si[256][K2];

    const int tid = threadIdx.x;
    const int mb  = (int)blockIdx.x >> 3;      // m*64 + b
    const int seg = (int)blockIdx.x & 7;
    const int b = mb & 63;
    const int m = mb >> 6;

    float v[K2]; int ix[K2];
    #pragma unroll
    for (int k = 0; k < K2; ++k) { v[k] = -INFINITY; ix[k] = 0x7fffffff; }

    const size_t roff = (size_t)b * NDB;
    const int iend = (seg + 1) * SEGSZ;
    for (int i = seg * SEGSZ + tid; i < iend; i += 256) {
        float sval;
        if (m == 0) {
            sval = (semp0[roff + i] + semp1[roff + i]) * (1.0f / sqrtf(nsq0[i] + nsq1[i]));
        } else {
            sval = dstp[roff + i] * (1.0f / sqrtf(nsqd[i]));
        }
        if (sval > v[0]) {
            bool bt[K2];
            bt[0] = true;
            #pragma unroll
            for (int j = 1; j < K2; ++j) bt[j] = sval > v[j];
            #pragma unroll
            for (int j = 0; j < K2 - 1; ++j) {
                v[j]  = bt[j+1] ? v[j+1]  : (bt[j] ? sval : v[j]);
                ix[j] = bt[j+1] ? ix[j+1] : (bt[j] ? i    : ix[j]);
            }
            v[K2-1]  = bt[K2-1] ? sval : v[K2-1];
            ix[K2-1] = bt[K2-1] ? i    : ix[K2-1];
        }
    }

    #pragma unroll
    for (int k = 0; k < K2; ++k) { sv[tid][k] = v[k]; si[tid][k] = ix[k]; }
    __syncthreads();

    for (int s2 = 128; s2 >= 1; s2 >>= 1) {
        if (tid < s2) {
            float rv[K2]; int ri[K2];
            int pa = K2 - 1, pb = K2 - 1;
            #pragma unroll
            for (int k = K2 - 1; k >= 0; --k) {
                const float va = sv[tid][pa];      const int ia = si[tid][pa];
                const float vb = sv[tid + s2][pb]; const int ib = si[tid + s2][pb];
                const bool takeA = (va > vb) || (va == vb && ia < ib);
                rv[k] = takeA ? va : vb;
                ri[k] = takeA ? ia : ib;
                if (takeA) --pa; else --pb;
            }
            #pragma unroll
            for (int k = 0; k < K2; ++k) { sv[tid][k] = rv[k]; si[tid][k] = ri[k]; }
        }
        __syncthreads();
    }

    if (tid < K2) {
        cand_val[(size_t)mb * 128 + seg * K2 + tid] = sv[0][K2 - 1 - tid];
        cand_idx[(size_t)mb * 128 + seg * K2 + tid] = si[0][K2 - 1 - tid];
    }
}

// ---------------------------------------------------------------------------
// merge: top-16 of the 128 segment candidates per (m,b) -> idx_ws. (R9 ✓)
// ---------------------------------------------------------------------------
__global__ __launch_bounds__(128) void merge_kernel(
    const float* __restrict__ cand_val, const int* __restrict__ cand_idx,
    int* __restrict__ idx_ws)
{
    __shared__ float v[128];
    __shared__ int   id[128];
    const int tid = threadIdx.x;
    const int mb  = (int)blockIdx.x;
    v[tid]  = cand_val[(size_t)mb * 128 + tid];
    id[tid] = cand_idx[(size_t)mb * 128 + tid];
    __syncthreads();
    const float mv = v[tid];
    const int   mi = id[tid];
    int rank = 0;
    for (int j = 0; j < 128; ++j)
        rank += (v[j] > mv) || (v[j] == mv && id[j] < mi);
    if (rank < K2) idx_ws[(size_t)mb * K2 + rank] = mi;
}

// ---------------------------------------------------------------------------
// rerank: exact fp32 cos for 16 candidates per (m,b); rank (desc, idx asc);
// top-9 -> metrics gather into retrieved[b][2j+m]. (rounds 7-9 ✓)
// ---------------------------------------------------------------------------
__global__ __launch_bounds__(256) void rerank_kernel(
    const float* __restrict__ fc, const float* __restrict__ fd,
    const float* __restrict__ sdb, const float* __restrict__ ddb,
    const int* __restrict__ idx_ws, const float* __restrict__ metrics,
    float* __restrict__ out_ret)
{
    __shared__ float cosv[K2];
    __shared__ int   cidx[K2];

    const int tid = threadIdx.x;
    const int lane = tid & 63, w = tid >> 6;
    const int bid = (int)blockIdx.x;
    const int b = bid & 63;
    const int m = bid >> 6;

    const float* Q  = (m == 0) ? fc + (size_t)b * KSEM : fd + (size_t)b * KDST;
    const float* DB = (m == 0) ? sdb : ddb;
    const int Ks = (m == 0) ? KSEM : KDST;
    const int nf4 = Ks / 4;

    for (int c = w; c < K2; c += 4) {
        const int idx = idx_ws[(size_t)bid * K2 + c];
        const float4* Q4 = (const float4*)Q;
        const float4* R4 = (const float4*)(DB + (size_t)idx * Ks);
        float dot = 0.f, sq = 0.f;
        for (int it = lane; it < nf4; it += 64) {
            const float4 qv = Q4[it];
            const float4 rv = R4[it];
            dot = fmaf(qv.x, rv.x, dot); sq = fmaf(rv.x, rv.x, sq);
            dot = fmaf(qv.y, rv.y, dot); sq = fmaf(rv.y, rv.y, sq);
            dot = fmaf(qv.z, rv.z, dot); sq = fmaf(rv.z, rv.z, sq);
            dot = fmaf(qv.w, rv.w, dot); sq = fmaf(rv.w, rv.w, sq);
        }
        #pragma unroll
        for (int off = 1; off < 64; off <<= 1) {
            dot += __shfl_xor(dot, off);
            sq  += __shfl_xor(sq,  off);
        }
        if (lane == 0) {
            cosv[c] = dot / sqrtf(sq);
            cidx[c] = idx;
        }
    }
    __syncthreads();

    if (tid < K2) {
        const float v = cosv[tid];
        const int   id = cidx[tid];
        int rank = 0;
        #pragma unroll
        for (int j = 0; j < K2; ++j)
            rank += (cosv[j] > v) || (cosv[j] == v && cidx[j] < id);
        if (rank < 9) out_ret[(size_t)b * 18 + 2 * rank + m] = metrics[id];
    }
}

// result[b] = mean(retrieved[b][0..17])
__global__ void finalize_kernel(float* __restrict__ d_out)
{
    const int b = threadIdx.x;
    const float* r = d_out + 64 + (size_t)b * 18;
    float s = 0.f;
    #pragma unroll
    for (int j = 0; j < 18; ++j) s += r[j];
    d_out[b] = s * (1.0f / 18.0f);
}

extern "C" void kernel_launch(void* const* d_in, const int* in_sizes, int n_in,
                              void* d_out, int out_size, void* d_ws, size_t ws_size,
                              hipStream_t stream)
{
    const float* fc  = (const float*)d_in[0];   // [64][4096]
    const float* fd  = (const float*)d_in[1];   // [64][2048]
    const float* sdb = (const float*)d_in[2];   // [20000][4096]
    const float* ddb = (const float*)d_in[3];   // [20000][2048]
    const float* met = (const float*)d_in[4];   // [20000]

    float* semp0 = (float*)d_ws;
    float* semp1 = semp0 + (size_t)NQ * NDB;
    float* dstp  = semp1 + (size_t)NQ * NDB;
    float* nsq0  = dstp  + (size_t)NQ * NDB;
    float* nsq1  = nsq0 + NDB;
    float* nsqd  = nsq1 + NDB;
    _Float16* apack_sem = (_Float16*)(nsqd + NDB);       // hi only: 512 KB
    _Float16* apack_dst = apack_sem + (size_t)NQ * KSEM; // hi only: 256 KB
    float* cand_val = (float*)(apack_dst + (size_t)NQ * KDST);  // 128*128
    int*   cand_idx = (int*)(cand_val + 128 * 128);             // 128*128
    int*   idx_ws   = cand_idx + 128 * 128;                     // 128*16

    float* out = (float*)d_out;

    qsplit_kernel<<<dim3(192), dim3(256), 0, stream>>>(fc, fd, apack_sem, apack_dst);
    score_kernel<<<dim3(3 * NTILE), dim3(256), 0, stream>>>(
        sdb, ddb, apack_sem, apack_dst, semp0, semp1, dstp, nsq0, nsq1, nsqd);
    topk_seg_kernel<<<dim3(128 * SEG), dim3(256), 0, stream>>>(
        semp0, semp1, dstp, nsq0, nsq1, nsqd, cand_val, cand_idx);
    merge_kernel<<<dim3(128), dim3(128), 0, stream>>>(cand_val, cand_idx, idx_ws);
    rerank_kernel<<<dim3(128), dim3(256), 0, stream>>>(
        fc, fd, sdb, ddb, idx_ws, met, out + 64);
    finalize_kernel<<<dim3(1), dim3(64), 0, stream>>>(out);
}

// Round 14
// 152.966 us; speedup vs baseline: 1.4178x; 1.4178x over previous
//
#include <hip/hip_runtime.h>
#include <math.h>

// NoRefRetIQANet: cosine top-K retrieval via fp16 2-split MFMA.
//   score[b,n] = dot(q_b, d_n) / ||d_n||  (query norm skipped: order-invariant)
//   x = hi + lo/4096;  dot = hh + (hl + lh)/4096  (ll term ~2^-24, dropped)
// Round-14: BN=128, K-step 32 -- per-WAVE step shape IDENTICAL to R12's
// proven rhythm (24 MFMA + 32 converts/wave-step), but A amortized over 2x
// columns: staged bytes 962 -> 724 MB. 471 blocks = 157 n-tiles x {sem kc0,
// sem kc1, dst}; 256 thr / 4 waves (2qh x 2nh, wave tile 32q x 64n);
// ring-2 LDS 48 KB; 6 DMA/wave/step, vmcnt(6) gate, two-barrier loop.
// Tail: R12 banked tail verbatim (segmented top-16 + merge-gather).
// ws: semp0[64][20000] f32, semp1, dstp, nsq0/1/d[20000], apack_sem(hi+lo),
//     apack_dst(hi+lo), cand_val[128][128], cand_idx[128][128].
// d_out: [0,64) result, [64, 64+64*18) retrieved.

typedef _Float16 half8 __attribute__((ext_vector_type(8)));
typedef float    f32x4 __attribute__((ext_vector_type(4)));

#define NDB   20000
#define NQ    64
#define KSEM  4096
#define KDST  2048
#define KC    2048
#define NSTEP (KC / 32)     // 64 steps of 32
#define BN    128
#define NTILE 157           // ceil(20000/128); last tile row-clamped
#define K2    16
#define SEG   8
#define SEGSZ (NDB / SEG)   // 2500

__device__ __forceinline__ void async_cp16(const void* g, void* l) {
    __builtin_amdgcn_global_load_lds(
        (const __attribute__((address_space(1))) void*)g,
        (__attribute__((address_space(3))) void*)l, 16, 0, 0);
}

// ---------------------------------------------------------------------------
// qsplit: fp32 queries -> fragment-ordered, bank-swizzled f16 hi/lo pack.
// Unit u (16B = half8) within a 32-k section: u = 4*row + (((row>>1)&3)^kg);
// section = 512 units: [0,256) hi, [256,512) lo.  (verified rounds 3-6, 12)
// ---------------------------------------------------------------------------
__global__ __launch_bounds__(256) void qsplit_kernel(
    const float* __restrict__ fc, const float* __restrict__ fd,
    _Float16* __restrict__ apack_sem, _Float16* __restrict__ apack_dst)
{
    const int idx = (int)blockIdx.x * 256 + (int)threadIdx.x;
    const int NSEM8 = NQ * KSEM / 8;            // 32768
    const float* src; _Float16* dst; int row, g8, K;
    if (idx < NSEM8) { src = fc; dst = apack_sem; K = KSEM; row = idx >> 9; g8 = idx & 511; }
    else { const int j = idx - NSEM8; src = fd; dst = apack_dst; K = KDST; row = j >> 8; g8 = j & 255; }

    const float* p = src + (size_t)row * K + g8 * 8;
    const float4 v0 = ((const float4*)p)[0];
    const float4 v1 = ((const float4*)p)[1];
    const float xs[8] = {v0.x, v0.y, v0.z, v0.w, v1.x, v1.y, v1.z, v1.w};
    half8 hi, lo;
    #pragma unroll
    for (int e = 0; e < 8; ++e) {
        const _Float16 h = (_Float16)xs[e];
        hi[e] = h;
        lo[e] = (_Float16)((xs[e] - (float)h) * 4096.0f);
    }
    const int sec = g8 >> 2, kg = g8 & 3;
    const int u = (row << 2) + (((row >> 1) & 3) ^ kg);
    half8* d8 = (half8*)dst;
    d8[sec * 512 + u]       = hi;
    d8[sec * 512 + 256 + u] = lo;
}

// ---------------------------------------------------------------------------
// score: 471 blocks = 157 n-tiles x {sem kc0, sem kc1, dst}, uniform KC=2048.
// 256 thr / 4 waves, wave grid 2x2 (qh=w>>1, nh=w&1), wave tile 32q x 64n.
// ---------------------------------------------------------------------------
__global__ __launch_bounds__(256, 2) void score_kernel(
    const float* __restrict__ sdb, const float* __restrict__ ddb,
    const _Float16* __restrict__ apack_sem, const _Float16* __restrict__ apack_dst,
    float* __restrict__ semp0, float* __restrict__ semp1, float* __restrict__ dstp,
    float* __restrict__ nsq0, float* __restrict__ nsq1, float* __restrict__ nsqd)
{
    // A: [buf][hi 2048 | lo 2048] halves; 8 KB/buf
    __shared__ __align__(16) _Float16 A_lds[2][4096];
    // B: [buf][r*32 + cphys*4] floats, 128 rows; 16 KB/buf
    __shared__ __align__(16) float    B_lds[2][4096];

    const int tid  = threadIdx.x;
    const int lane = tid & 63, w = tid >> 6;
    const int bid  = (int)blockIdx.x;
    const int mkc  = bid / NTILE;         // 0: sem kc0, 1: sem kc1, 2: dst
    const int nt   = bid % NTILE;
    const int n0   = nt * BN;

    const float* D; const _Float16* AP; float *SOUT, *NOUT; int Ks, koff;
    if (mkc == 0)      { D=sdb; AP=apack_sem; SOUT=semp0; NOUT=nsq0; Ks=KSEM; koff=0;  }
    else if (mkc == 1) { D=sdb; AP=apack_sem; SOUT=semp1; NOUT=nsq1; Ks=KSEM; koff=KC; }
    else               { D=ddb; AP=apack_dst; SOUT=dstp;  NOUT=nsqd; Ks=KDST; koff=0;  }

    // --- B staging: 16 insts/step, 4 per wave; unit u = w*256 + k2*64 + lane
    const float* gBp[4];
    #pragma unroll
    for (int k2 = 0; k2 < 4; ++k2) {
        const int u = w * 256 + k2 * 64 + lane;
        const int r = u >> 3;
        const int c = (u & 7) ^ (r & 7);
        const int rg = (n0 + r < NDB) ? n0 + r : NDB - 1;   // clamp tail tile
        gBp[k2] = D + (size_t)rg * Ks + koff + c * 4;
    }
    // --- A staging: 2 insts/wave; hi units w*64+lane, lo at +256
    const uint4* gA = (const uint4*)AP + ((size_t)koff >> 5) * 512 + w * 64 + lane;

    // --- compute map ---
    const int lr = lane & 15, kg = lane >> 4;
    const int qh = w >> 1, nh = w & 1;
    const int rowA0 = qh * 32 + lr;
    const int rowA1 = rowA0 + 16;
    const int uA0 = ((rowA0 << 2) + (((rowA0 >> 1) & 3) ^ kg)) * 8;
    const int uA1 = ((rowA1 << 2) + (((rowA1 >> 1) & 3) ^ kg)) * 8;
    int oB0[4], oB1[4];
    #pragma unroll
    for (int j = 0; j < 4; ++j) {
        const int rB = nh * 64 + j * 16 + lr;
        oB0[j] = rB * 32 + (((kg * 2 + 0) ^ (rB & 7)) << 2);
        oB1[j] = rB * 32 + (((kg * 2 + 1) ^ (rB & 7)) << 2);
    }

    f32x4 acc_h[2][4], acc_x[2][4];
    const f32x4 zz = {0.f, 0.f, 0.f, 0.f};
    #pragma unroll
    for (int i = 0; i < 2; ++i)
        #pragma unroll
        for (int j = 0; j < 4; ++j) { acc_h[i][j] = zz; acc_x[i][j] = zz; }
    float sq[4] = {0.f, 0.f, 0.f, 0.f};

    auto STAGE = [&](int s, int buf) {
        async_cp16(gA + (size_t)s * 512,       &A_lds[buf][w * 512]);         // hi
        async_cp16(gA + (size_t)s * 512 + 256, &A_lds[buf][2048 + w * 512]);  // lo
        #pragma unroll
        for (int k2 = 0; k2 < 4; ++k2)
            async_cp16(gBp[k2] + (size_t)s * 32, &B_lds[buf][w * 1024 + k2 * 256]);
    };

    auto COMPUTE = [&](int buf) {
        const float*    Bb = &B_lds[buf][0];
        const _Float16* Ab = &A_lds[buf][0];
        half8 bh[4], bl[4];
        #pragma unroll
        for (int j = 0; j < 4; ++j) {
            const f32x4 p = *(const f32x4*)(Bb + oB0[j]);
            const f32x4 q = *(const f32x4*)(Bb + oB1[j]);
            const float xs[8] = {p[0], p[1], p[2], p[3], q[0], q[1], q[2], q[3]};
            #pragma unroll
            for (int e = 0; e < 8; ++e) {
                const float x = xs[e];
                sq[j] = fmaf(x, x, sq[j]);
                const _Float16 h = (_Float16)x;
                bh[j][e] = h;
                bl[j][e] = (_Float16)((x - (float)h) * 4096.0f);
            }
        }
        const half8 ah0 = *(const half8*)(Ab + uA0);
        const half8 av0 = *(const half8*)(Ab + 2048 + uA0);
        const half8 ah1 = *(const half8*)(Ab + uA1);
        const half8 av1 = *(const half8*)(Ab + 2048 + uA1);
        #pragma unroll
        for (int j = 0; j < 4; ++j) {
            acc_h[0][j] = __builtin_amdgcn_mfma_f32_16x16x32_f16(ah0, bh[j], acc_h[0][j], 0, 0, 0);
            acc_x[0][j] = __builtin_amdgcn_mfma_f32_16x16x32_f16(ah0, bl[j], acc_x[0][j], 0, 0, 0);
            acc_x[0][j] = __builtin_amdgcn_mfma_f32_16x16x32_f16(av0, bh[j], acc_x[0][j], 0, 0, 0);
            acc_h[1][j] = __builtin_amdgcn_mfma_f32_16x16x32_f16(ah1, bh[j], acc_h[1][j], 0, 0, 0);
            acc_x[1][j] = __builtin_amdgcn_mfma_f32_16x16x32_f16(ah1, bl[j], acc_x[1][j], 0, 0, 0);
            acc_x[1][j] = __builtin_amdgcn_mfma_f32_16x16x32_f16(av1, bh[j], acc_x[1][j], 0, 0, 0);
        }
    };

    // prologue: 2 steps staged (12 DMAs/wave outstanding)
    STAGE(0, 0); STAGE(1, 1);

    for (int s = 0; s < NSTEP; ++s) {
        if (s < NSTEP - 1) { asm volatile("s_waitcnt vmcnt(6)" ::: "memory"); }
        else               { asm volatile("s_waitcnt vmcnt(0)" ::: "memory"); }
        __builtin_amdgcn_s_barrier();      // step-s data visible to all waves
        COMPUTE(s & 1);
        __builtin_amdgcn_s_barrier();      // all waves done reading buf s&1
        if (s + 2 < NSTEP) STAGE(s + 2, s & 1);
    }

    // norms (exact f32 sum-sq of raw B): sq[j] covers col nh*64+j*16+lr over
    // this lane's kg quarter; reduce over kg (xor 16,32); qh==0 waves write.
    #pragma unroll
    for (int j = 0; j < 4; ++j) {
        sq[j] += __shfl_xor(sq[j], 16);
        sq[j] += __shfl_xor(sq[j], 32);
    }
    if (qh == 0 && lane < 16) {
        #pragma unroll
        for (int j = 0; j < 4; ++j) {
            const int nn = n0 + nh * 64 + j * 16 + lane;
            if (nn < NDB) NOUT[nn] = sq[j];
        }
    }

    // C/D map: col=lane&15, row=(lane>>4)*4+reg (m89-verified)
    #pragma unroll
    for (int i = 0; i < 2; ++i)
        #pragma unroll
        for (int j = 0; j < 4; ++j) {
            const int n = n0 + nh * 64 + j * 16 + lr;
            if (n < NDB) {
                #pragma unroll
                for (int rr = 0; rr < 4; ++rr) {
                    const int q = qh * 32 + i * 16 + kg * 4 + rr;
                    SOUT[(size_t)q * NDB + n] = acc_h[i][j][rr] + acc_x[i][j][rr] * (1.0f / 4096.0f);
                }
            }
        }
}

// ---------------------------------------------------------------------------
// topk_seg: EXACT top-16 per (m,b,segment). 1024 blocks. (R12 verbatim)
// Comparator: value desc, index asc (matches lax.top_k).
// ---------------------------------------------------------------------------
__global__ __launch_bounds__(256) void topk_seg_kernel(
    const float* __restrict__ semp0, const float* __restrict__ semp1,
    const float* __restrict__ dstp,
    const float* __restrict__ nsq0, const float* __restrict__ nsq1,
    const float* __restrict__ nsqd,
    float* __restrict__ cand_val, int* __restrict__ cand_idx)
{
    __shared__ float sv[256][K2];
    __shared__ int   si[256][K2];

    const int tid = threadIdx.x;
    const int mb  = (int)blockIdx.x >> 3;      // m*64 + b
    const int seg = (int)blockIdx.x & 7;
    const int b = mb & 63;
    const int m = mb >> 6;

    float v[K2]; int ix[K2];
    #pragma unroll
    for (int k = 0; k < K2; ++k) { v[k] = -INFINITY; ix[k] = 0x7fffffff; }

    const size_t roff = (size_t)b * NDB;
    const int iend = (seg + 1) * SEGSZ;
    for (int i = seg * SEGSZ + tid; i < iend; i += 256) {
        float sval;
        if (m == 0) {
            sval = (semp0[roff + i] + semp1[roff + i]) * (1.0f / sqrtf(nsq0[i] + nsq1[i]));
        } else {
            sval = dstp[roff + i] * (1.0f / sqrtf(nsqd[i]));
        }
        if (sval > v[0]) {
            bool bt[K2];
            bt[0] = true;
            #pragma unroll
            for (int j = 1; j < K2; ++j) bt[j] = sval > v[j];
            #pragma unroll
            for (int j = 0; j < K2 - 1; ++j) {
                v[j]  = bt[j+1] ? v[j+1]  : (bt[j] ? sval : v[j]);
                ix[j] = bt[j+1] ? ix[j+1] : (bt[j] ? i    : ix[j]);
            }
            v[K2-1]  = bt[K2-1] ? sval : v[K2-1];
            ix[K2-1] = bt[K2-1] ? i    : ix[K2-1];
        }
    }

    #pragma unroll
    for (int k = 0; k < K2; ++k) { sv[tid][k] = v[k]; si[tid][k] = ix[k]; }
    __syncthreads();

    for (int s2 = 128; s2 >= 1; s2 >>= 1) {
        if (tid < s2) {
            float rv[K2]; int ri[K2];
            int pa = K2 - 1, pb = K2 - 1;
            #pragma unroll
            for (int k = K2 - 1; k >= 0; --k) {
                const float va = sv[tid][pa];      const int ia = si[tid][pa];
                const float vb = sv[tid + s2][pb]; const int ib = si[tid + s2][pb];
                const bool takeA = (va > vb) || (va == vb && ia < ib);
                rv[k] = takeA ? va : vb;
                ri[k] = takeA ? ia : ib;
                if (takeA) --pa; else --pb;
            }
            #pragma unroll
            for (int k = 0; k < K2; ++k) { sv[tid][k] = rv[k]; si[tid][k] = ri[k]; }
        }
        __syncthreads();
    }

    if (tid < K2) {
        cand_val[(size_t)mb * 128 + seg * K2 + tid] = sv[0][K2 - 1 - tid];
        cand_idx[(size_t)mb * 128 + seg * K2 + tid] = si[0][K2 - 1 - tid];
    }
}

// ---------------------------------------------------------------------------
// merge: rank the 128 segment candidates per (m,b); rank<9 gathers metrics
// straight into retrieved[b][2*rank+m]. (R12 verbatim)
// ---------------------------------------------------------------------------
__global__ __launch_bounds__(128) void merge_kernel(
    const float* __restrict__ cand_val, const int* __restrict__ cand_idx,
    const float* __restrict__ metrics, float* __restrict__ out_ret)
{
    __shared__ float v[128];
    __shared__ int   id[128];
    const int tid = threadIdx.x;
    const int mb  = (int)blockIdx.x;
    const int b = mb & 63;
    const int m = mb >> 6;
    v[tid]  = cand_val[(size_t)mb * 128 + tid];
    id[tid] = cand_idx[(size_t)mb * 128 + tid];
    __syncthreads();
    const float mv = v[tid];
    const int   mi = id[tid];
    int rank = 0;
    for (int j = 0; j < 128; ++j)
        rank += (v[j] > mv) || (v[j] == mv && id[j] < mi);
    if (rank < 9) out_ret[(size_t)b * 18 + 2 * rank + m] = metrics[mi];
}

// result[b] = mean(retrieved[b][0..17])
__global__ void finalize_kernel(float* __restrict__ d_out)
{
    const int b = threadIdx.x;
    const float* r = d_out + 64 + (size_t)b * 18;
    float s = 0.f;
    #pragma unroll
    for (int j = 0; j < 18; ++j) s += r[j];
    d_out[b] = s * (1.0f / 18.0f);
}

extern "C" void kernel_launch(void* const* d_in, const int* in_sizes, int n_in,
                              void* d_out, int out_size, void* d_ws, size_t ws_size,
                              hipStream_t stream)
{
    const float* fc  = (const float*)d_in[0];   // [64][4096]
    const float* fd  = (const float*)d_in[1];   // [64][2048]
    const float* sdb = (const float*)d_in[2];   // [20000][4096]
    const float* ddb = (const float*)d_in[3];   // [20000][2048]
    const float* met = (const float*)d_in[4];   // [20000]

    float* semp0 = (float*)d_ws;
    float* semp1 = semp0 + (size_t)NQ * NDB;
    float* dstp  = semp1 + (size_t)NQ * NDB;
    float* nsq0  = dstp  + (size_t)NQ * NDB;
    float* nsq1  = nsq0 + NDB;
    float* nsqd  = nsq1 + NDB;
    _Float16* apack_sem = (_Float16*)(nsqd + NDB);           // hi+lo: 1 MB
    _Float16* apack_dst = apack_sem + (size_t)NQ * KSEM * 2; // hi+lo: 0.5 MB
    float* cand_val = (float*)(apack_dst + (size_t)NQ * KDST * 2);  // 128*128
    int*   cand_idx = (int*)(cand_val + 128 * 128);                 // 128*128

    float* out = (float*)d_out;

    qsplit_kernel<<<dim3(192), dim3(256), 0, stream>>>(fc, fd, apack_sem, apack_dst);
    score_kernel<<<dim3(3 * NTILE), dim3(256), 0, stream>>>(
        sdb, ddb, apack_sem, apack_dst, semp0, semp1, dstp, nsq0, nsq1, nsqd);
    topk_seg_kernel<<<dim3(128 * SEG), dim3(256), 0, stream>>>(
        semp0, semp1, dstp, nsq0, nsq1, nsqd, cand_val, cand_idx);
    merge_kernel<<<dim3(128), dim3(128), 0, stream>>>(cand_val, cand_idx, met, out + 64);
    finalize_kernel<<<dim3(1), dim3(64), 0, stream>>>(out);
}